// Round 1
// baseline (732.385 us; speedup 1.0000x reference)
//
#include <hip/hip_runtime.h>
#include <hip/hip_bf16.h>

#define B_   16
#define K_   50
#define CIN  256
#define F_   76
#define A_   3
#define NCH  85
#define OC   255
#define HW   (F_*F_)

// ws layout (floats): Wt[256*256] @ 0 ; biasPad[256] @ 65536 ; labrec[800*16] @ 65792
#define WS_BIAS 65536
#define WS_LAB  65792

__device__ __constant__ float AW9[9] = {1.25f, 2.0f, 4.125f, 3.75f, 7.75f, 7.375f, 14.5f, 19.5f, 46.625f};
__device__ __constant__ float AH9[9] = {1.625f, 3.75f, 2.875f, 7.625f, 5.625f, 14.875f, 11.25f, 24.75f, 40.75f};

__device__ __forceinline__ float sigm(float r) { return 1.0f / (1.0f + __expf(-r)); }

__device__ __forceinline__ float bce_t(float p, float tv) {
    float pc = fminf(fmaxf(p, 1e-12f), 1.0f - 1e-7f);
    return -(tv * __logf(pc) + (1.0f - tv) * __logf(1.0f - pc));
}

// ---------------- prep: transpose W, pad bias, zero scalars, label records ----------------
__global__ void prep_kernel(const float* __restrict__ conv_w, const float* __restrict__ conv_b,
                            const float* __restrict__ labels, float* __restrict__ ws,
                            float* __restrict__ d_out) {
    int bid = blockIdx.x, t = threadIdx.x;
    if (bid < 256) {
        // Wt[c][o], c = bid, o = t ; pad o=255 with 0
        ws[bid * 256 + t] = (t < OC) ? conv_w[t * CIN + bid] : 0.0f;
    } else if (bid == 256) {
        ws[WS_BIAS + t] = (t < OC) ? conv_b[t] : 0.0f;
        if (t < 6) d_out[t] = 0.0f;
    } else { // bid == 257 : label records
        for (int idx = t; idx < B_ * K_; idx += 256) {
            const float* L = labels + idx * 5;
            float cls = L[0], xc = L[1], yc = L[2], wl = L[3], hl = L[4];
            float ssum = cls + xc + yc + wl + hl;
            float validf = (ssum > 0.0f) ? 1.0f : 0.0f;
            float tx = xc * F_, ty = yc * F_, tw = wl * F_, th = hl * F_;
            int ii = (int)tx, jj = (int)ty;
            float tarea = tw * th;
            float best = -1.0f; int bn = 0;
            #pragma unroll
            for (int n = 0; n < 9; n++) {
                float inter = fminf(tw, AW9[n]) * fminf(th, AH9[n]);
                float iou = inter / (tarea + AW9[n] * AH9[n] - inter);
                if (iou > best) { best = iou; bn = n; }   // strict > == jnp.argmax first-max
            }
            int a = bn % 3;
            float self = (validf != 0.0f && bn < 3) ? 1.0f : 0.0f;
            float* R = ws + WS_LAB + idx * 16;
            R[0] = validf; R[1] = tx; R[2] = ty; R[3] = tw; R[4] = th;
            R[5] = self; R[6] = (float)a; R[7] = (float)ii; R[8] = (float)jj;
            R[9] = tx - (float)ii; R[10] = ty - (float)jj;
            R[11] = __logf(tw / AW9[a] + 1e-16f);
            R[12] = __logf(th / AH9[a] + 1e-16f);
            R[13] = sqrtf(2.0f - tarea / (float)HW);
            R[14] = cls; R[15] = 0.0f;
        }
    }
}

// ---------------- fused main: conv + activations + ignore/targets + losses + out_m ----------------
__global__ __launch_bounds__(256, 3) void yolo_main(const float* __restrict__ xin,
                                                    const float* __restrict__ ws,
                                                    float* __restrict__ d_out) {
    __shared__ __align__(16) float Xs[128 * 80];      // 40960 B, K-chunked input tile
    __shared__ float labS[K_ * 16];                   // 3200 B
    __hip_bfloat16* rawS = reinterpret_cast<__hip_bfloat16*>(Xs); // 255*80 bf16 = 40800 B (aliases Xs)

    const int t = threadIdx.x;
    const int b = blockIdx.x / F_;
    const int j = blockIdx.x % F_;

    const float* Wt    = ws;
    const float* biasP = ws + WS_BIAS;
    const float* labrec = ws + WS_LAB + b * K_ * 16;

    // load label records for this batch
    for (int idx = t; idx < K_ * 16; idx += 256) labS[idx] = labrec[idx];

    // cooperative zero of this block's out_m slabs (3 anchors x 76 i x 85 ch)
    for (int a = 0; a < A_; a++) {
        float2* z = reinterpret_cast<float2*>(d_out + 6 + (size_t)(((b * A_ + a) * F_ + j)) * F_ * NCH);
        for (int idx = t; idx < (F_ * NCH) / 2; idx += 256) z[idx] = make_float2(0.0f, 0.0f);
    }

    // ---------- phase 1: conv (255 outputs x 76 positions), 4o x 4i register tiles ----------
    float acc[5][16];
    #pragma unroll
    for (int n = 0; n < 5; n++)
        #pragma unroll
        for (int q = 0; q < 16; q++) acc[n][q] = 0.0f;

    int iog[5], iig[5];
    #pragma unroll
    for (int n = 0; n < 5; n++) { int item = t + n * 256; iog[n] = item / 20; iig[n] = item % 20; }

    for (int ck = 0; ck < 2; ck++) {
        __syncthreads();
        const float4* xsrc = reinterpret_cast<const float4*>(xin + ((size_t)b * CIN + ck * 128) * HW + j * F_);
        for (int idx = t; idx < 128 * 19; idx += 256) {
            int c = idx / 19, q = idx - c * 19;
            reinterpret_cast<float4*>(Xs)[c * 20 + q] = xsrc[c * (HW / 4) + q];
        }
        __syncthreads();
        #pragma unroll
        for (int n = 0; n < 5; n++) {
            const float4* wp = reinterpret_cast<const float4*>(Wt + ck * 128 * 256) + iog[n];
            const float4* xp = reinterpret_cast<const float4*>(Xs) + iig[n];
            #pragma unroll 4
            for (int c = 0; c < 128; c++) {
                float4 wv = wp[c * 64];   // Wt[ck*128+c][og*4 .. +3]
                float4 xv = xp[c * 20];   // Xs[c][ig*4 .. +3]
                acc[n][ 0] += wv.x * xv.x; acc[n][ 1] += wv.x * xv.y; acc[n][ 2] += wv.x * xv.z; acc[n][ 3] += wv.x * xv.w;
                acc[n][ 4] += wv.y * xv.x; acc[n][ 5] += wv.y * xv.y; acc[n][ 6] += wv.y * xv.z; acc[n][ 7] += wv.y * xv.w;
                acc[n][ 8] += wv.z * xv.x; acc[n][ 9] += wv.z * xv.y; acc[n][10] += wv.z * xv.z; acc[n][11] += wv.z * xv.w;
                acc[n][12] += wv.w * xv.x; acc[n][13] += wv.w * xv.y; acc[n][14] += wv.w * xv.z; acc[n][15] += wv.w * xv.w;
            }
        }
    }
    __syncthreads();
    // write raw (+bias) to LDS as bf16, layout raw[o][80] (aliases Xs)
    #pragma unroll
    for (int n = 0; n < 5; n++) {
        int og = iog[n], ig = iig[n];
        if (ig < 19) {
            #pragma unroll
            for (int oo = 0; oo < 4; oo++) {
                int o = og * 4 + oo;
                if (o < OC) {
                    float bv = biasP[o];
                    #pragma unroll
                    for (int i2 = 0; i2 < 4; i2++) {
                        int i = ig * 4 + i2;
                        rawS[o * 80 + i] = __float2bfloat16(acc[n][oo * 4 + i2] + bv);
                    }
                }
            }
        }
    }
    __syncthreads();

    // ---------- phase 2: per-cell losses + out_m ----------
    float lxy = 0.0f, lwh = 0.0f, lobj = 0.0f, lcls = 0.0f, l2 = 0.0f;
    if (t < A_ * F_) {
        int a = t / F_, i = t - a * F_;
        const __hip_bfloat16* rc = rawS + (a * NCH) * 80 + i;
        float x   = sigm(__bfloat162float(rc[0 * 80]));
        float y   = sigm(__bfloat162float(rc[1 * 80]));
        float wr  = __bfloat162float(rc[2 * 80]);
        float hr  = __bfloat162float(rc[3 * 80]);
        float obj = sigm(__bfloat162float(rc[4 * 80]));

        float px = x + (float)i, py = y + (float)j;
        float pw = __expf(wr) * AW9[a], ph = __expf(hr) * AH9[a];
        float areap = pw * ph;

        float maxiou = 0.0f; int mk = -1;
        for (int k = 0; k < K_; k++) {
            const float* R = labS + k * 16;
            float tx = R[1], ty = R[2], tw = R[3], th = R[4];
            if (R[0] != 0.0f) {
                float tlx = fmaxf(px - pw * 0.5f, tx - tw * 0.5f);
                float tly = fmaxf(py - ph * 0.5f, ty - th * 0.5f);
                float brx = fminf(px + pw * 0.5f, tx + tw * 0.5f);
                float bry = fminf(py + ph * 0.5f, ty + th * 0.5f);
                float iw = brx - tlx, ih = bry - tly;
                float inter = (iw > 0.0f && ih > 0.0f) ? iw * ih : 0.0f;
                float iou = inter / (areap + tw * th - inter);
                maxiou = fmaxf(maxiou, iou);
            }
            if (R[5] != 0.0f && (int)R[6] == a && (int)R[7] == i && (int)R[8] == j) mk = k; // last wins
        }
        float objmask = (maxiou > 0.7f) ? 0.0f : 1.0f;

        float* om = d_out + 6 + (size_t)(((b * A_ + a) * F_ + j) * F_ + i) * NCH;
        if (mk >= 0) {
            const float* R = labS + mk * 16;
            float sc = R[13], sc2 = sc * sc;
            float txv = R[9], tyv = R[10], twv = R[11], thv = R[12];
            int cl = (int)R[14];
            lxy = (bce_t(x, txv) + bce_t(y, tyv)) * sc2;
            float dw = wr - twv, dh = hr - thv;
            lwh = 0.5f * sc2 * (dw * dw + dh * dh);
            float pco = fminf(fmaxf(obj, 1e-12f), 1.0f - 1e-7f);
            lobj = -__logf(pco);
            float dx = x - txv, dy = y - tyv, dob = obj - 1.0f;
            l2 = dx * dx + dy * dy + sc2 * (dw * dw + dh * dh) + dob * dob;
            om[0] = x; om[1] = y; om[2] = wr * sc; om[3] = hr * sc; om[4] = obj;
            for (int c = 0; c < 80; c++) {
                float p = sigm(__bfloat162float(rc[(5 + c) * 80]));
                float tcv = (c == cl) ? 1.0f : 0.0f;
                lcls += bce_t(p, tcv);
                float d = p - tcv;
                l2 += d * d;
                om[5 + c] = p;
            }
        } else {
            float oo = obj * objmask;
            if (objmask != 0.0f) {
                float pco = fminf(obj, 1.0f - 1e-7f);
                lobj = -__logf(1.0f - pco);
            }
            l2 = oo * oo;
            om[4] = oo;    // rest already zero-filled
        }
    }

    // wave reduction + atomics
    #pragma unroll
    for (int off = 32; off > 0; off >>= 1) {
        lxy  += __shfl_down(lxy, off);
        lwh  += __shfl_down(lwh, off);
        lobj += __shfl_down(lobj, off);
        lcls += __shfl_down(lcls, off);
        l2   += __shfl_down(l2, off);
    }
    if ((t & 63) == 0) {
        atomicAdd(&d_out[1], lxy);
        atomicAdd(&d_out[2], lwh);
        atomicAdd(&d_out[3], lobj);
        atomicAdd(&d_out[4], lcls);
        atomicAdd(&d_out[5], l2);
        atomicAdd(&d_out[0], lxy + lwh + lobj + lcls);
    }
}

extern "C" void kernel_launch(void* const* d_in, const int* in_sizes, int n_in,
                              void* d_out, int out_size, void* d_ws, size_t ws_size,
                              hipStream_t stream) {
    const float* xin    = (const float*)d_in[0];
    const float* labels = (const float*)d_in[1];
    const float* conv_w = (const float*)d_in[2];
    const float* conv_b = (const float*)d_in[3];
    float* out = (float*)d_out;
    float* ws  = (float*)d_ws;

    prep_kernel<<<258, 256, 0, stream>>>(conv_w, conv_b, labels, ws, out);
    yolo_main<<<B_ * F_, 256, 0, stream>>>(xin, ws, out);
}

// Round 2
// 585.858 us; speedup vs baseline: 1.2501x; 1.2501x over previous
//
#include <hip/hip_runtime.h>
#include <hip/hip_bf16.h>

#define B_   16
#define K_   50
#define CIN  256
#define F_   76
#define A_   3
#define NCH  85
#define OC   255
#define HW   (F_*F_)

// ws layout: Wfrag bf16[65536] = float[0..32768) ; bias float[32768..33024) ; labrec float[33024..45824)
#define WS_BIAS_F 32768
#define WS_LAB_F  33024

typedef __attribute__((ext_vector_type(8))) short short8;
typedef __attribute__((ext_vector_type(4))) float f32x4;

__device__ __constant__ float AW9[9] = {1.25f, 2.0f, 4.125f, 3.75f, 7.75f, 7.375f, 14.5f, 19.5f, 46.625f};
__device__ __constant__ float AH9[9] = {1.625f, 3.75f, 2.875f, 7.625f, 5.625f, 14.875f, 11.25f, 24.75f, 40.75f};

__device__ __forceinline__ unsigned short f2bf(float f) {
    union { float f; unsigned int u; } v; v.f = f;
    unsigned int r = v.u + 0x7fffu + ((v.u >> 16) & 1u);   // RNE, matches HW cvt
    return (unsigned short)(r >> 16);
}
__device__ __forceinline__ float bf2f(unsigned short b) {
    union { unsigned int u; float f; } v; v.u = ((unsigned int)b) << 16;
    return v.f;
}
__device__ __forceinline__ float sigm(float r) { return 1.0f / (1.0f + __expf(-r)); }
__device__ __forceinline__ float bce_t(float p, float tv) {
    float pc = fminf(fmaxf(p, 1e-12f), 1.0f - 1e-7f);
    return -(tv * __logf(pc) + (1.0f - tv) * __logf(1.0f - pc));
}

// ---------------- prep: W -> bf16 A-fragment order, bias, scalars, label records ----------------
// Wfrag layout: [mt(16)][ks(8)][lane(64)][jj(8)] bf16 ; element = W[mt*16 + (lane&15)][ks*32 + (lane>>4)*8 + jj]
__global__ void prep_kernel(const float* __restrict__ conv_w, const float* __restrict__ conv_b,
                            const float* __restrict__ labels, float* __restrict__ ws,
                            float* __restrict__ d_out) {
    int bid = blockIdx.x, t = threadIdx.x;
    if (bid < 256) {
        int idx = bid * 256 + t;                 // 0..65535
        int mt = idx >> 12, ks = (idx >> 9) & 7, lane = (idx >> 3) & 63, jj = idx & 7;
        int row = mt * 16 + (lane & 15);
        int k   = ks * 32 + (lane >> 4) * 8 + jj;
        float v = (row < OC) ? conv_w[row * CIN + k] : 0.0f;
        ((unsigned short*)ws)[idx] = f2bf(v);
    } else if (bid == 256) {
        ws[WS_BIAS_F + t] = (t < OC) ? conv_b[t] : 0.0f;
        if (t < 6) d_out[t] = 0.0f;
    } else { // label records
        for (int idx = t; idx < B_ * K_; idx += 256) {
            const float* L = labels + idx * 5;
            float cls = L[0], xc = L[1], yc = L[2], wl = L[3], hl = L[4];
            float ssum = cls + xc + yc + wl + hl;
            float validf = (ssum > 0.0f) ? 1.0f : 0.0f;
            float tx = xc * F_, ty = yc * F_, tw = wl * F_, th = hl * F_;
            int ii = (int)tx, jj = (int)ty;
            float tarea = tw * th;
            float best = -1.0f; int bn = 0;
            #pragma unroll
            for (int n = 0; n < 9; n++) {
                float inter = fminf(tw, AW9[n]) * fminf(th, AH9[n]);
                float iou = inter / (tarea + AW9[n] * AH9[n] - inter);
                if (iou > best) { best = iou; bn = n; }
            }
            int a = bn % 3;
            float self = (validf != 0.0f && bn < 3) ? 1.0f : 0.0f;
            float* R = ws + WS_LAB_F + idx * 16;
            R[0] = validf; R[1] = tx; R[2] = ty; R[3] = tw; R[4] = th;
            R[5] = self; R[6] = (float)a; R[7] = (float)ii; R[8] = (float)jj;
            R[9] = tx - (float)ii; R[10] = ty - (float)jj;
            R[11] = __logf(tw / AW9[a] + 1e-16f);
            R[12] = __logf(th / AH9[a] + 1e-16f);
            R[13] = sqrtf(2.0f - tarea / (float)HW);
            R[14] = cls; R[15] = 0.0f;
        }
    }
}

// ---------------- fused main: MFMA conv + activations + ignore/targets + losses + out_m ----------------
__global__ __launch_bounds__(256, 3) void yolo_main(const float* __restrict__ xin,
                                                    const float* __restrict__ ws,
                                                    float* __restrict__ d_out) {
    // UNI: phase 1 = Xt bf16 [n=80][k=256] octet-XOR-swizzled (20480 ush used)
    //      phase 2 = raw bf16 [o=255][i stride 84] (21420 ush)
    __shared__ __align__(16) unsigned short UNI[OC * 84];    // 42840 B
    __shared__ float labS[K_ * 16];                          // 3200 B
    __shared__ float biasS[256];                             // 1024 B

    const int t = threadIdx.x;
    const int b = blockIdx.x / F_;
    const int j = blockIdx.x % F_;
    const unsigned short* wfragU = (const unsigned short*)ws;
    const float* labrec = ws + WS_LAB_F + b * K_ * 16;

    biasS[t < 256 ? t : 0] = ws[WS_BIAS_F + t];
    for (int idx = t; idx < K_ * 16; idx += 256) labS[idx] = labrec[idx];

    // cooperative zero of this block's out_m slabs
    for (int a = 0; a < A_; a++) {
        float2* z = reinterpret_cast<float2*>(d_out + 6 + (size_t)(((b * A_ + a) * F_ + j)) * F_ * NCH);
        for (int idx = t; idx < (F_ * NCH) / 2; idx += 256) z[idx] = make_float2(0.0f, 0.0f);
    }

    // ---------- staging: xin row j -> Xt[i][c] bf16, k-contiguous octets, XOR-swizzled ----------
    // item = (co 0..31, i 0..75): lane-consecutive i => coalesced global; phys = co ^ (i&7) => conflict-free LDS
    for (int idx = t; idx < 32 * F_; idx += 256) {
        int co = idx / F_, i = idx - co * F_;
        const float* xp = xin + ((size_t)b * CIN + co * 8) * HW + j * F_ + i;
        short8 v;
        #pragma unroll
        for (int jj = 0; jj < 8; jj++) v[jj] = (short)f2bf(xp[jj * HW]);
        int phys = co ^ (i & 7);
        *(short8*)&UNI[i * 256 + phys * 8] = v;
    }
    __syncthreads();

    // ---------- MFMA K-loop: wave w owns M-tiles w*4..w*4+3, all 5 N-tiles ----------
    const int w = t >> 6, lane = t & 63, lr = lane & 15, q = lane >> 4;
    f32x4 acc[4][5];
    #pragma unroll
    for (int m = 0; m < 4; m++)
        #pragma unroll
        for (int n = 0; n < 5; n++) acc[m][n] = (f32x4){0.0f, 0.0f, 0.0f, 0.0f};

    const short8* wf = (const short8*)wfragU;
    #pragma unroll 2
    for (int ks = 0; ks < 8; ks++) {
        short8 afr[4], bfr[5];
        #pragma unroll
        for (int m = 0; m < 4; m++)
            afr[m] = wf[((w * 4 + m) * 8 + ks) * 64 + lane];
        #pragma unroll
        for (int n = 0; n < 5; n++) {
            int nn = n * 16 + lr;
            int phys = (ks * 4 + q) ^ (lr & 7);
            bfr[n] = *(const short8*)&UNI[nn * 256 + phys * 8];
        }
        #pragma unroll
        for (int m = 0; m < 4; m++)
            #pragma unroll
            for (int n = 0; n < 5; n++)
                acc[m][n] = __builtin_amdgcn_mfma_f32_16x16x32_bf16(afr[m], bfr[n], acc[m][n], 0, 0, 0);
    }
    __syncthreads();   // all B-reads done before overwriting UNI with raw

    // ---------- epilogue: acc (+bias) -> raw bf16 [o][i], stride 84 ----------
    #pragma unroll
    for (int m = 0; m < 4; m++) {
        #pragma unroll
        for (int n = 0; n < 5; n++) {
            int i = n * 16 + lr;
            if (i < F_) {
                #pragma unroll
                for (int r = 0; r < 4; r++) {
                    int o = (w * 4 + m) * 16 + q * 4 + r;
                    if (o < OC) UNI[o * 84 + i] = f2bf(acc[m][n][r] + biasS[o]);
                }
            }
        }
    }
    __syncthreads();

    // ---------- phase 2: per-cell losses + out_m ----------
    float lxy = 0.0f, lwh = 0.0f, lobj = 0.0f, lcls = 0.0f, l2 = 0.0f;
    if (t < A_ * F_) {
        int a = t / F_, i = t - a * F_;
        const unsigned short* rc = UNI + (a * NCH) * 84 + i;
        float x   = sigm(bf2f(rc[0 * 84]));
        float y   = sigm(bf2f(rc[1 * 84]));
        float wr  = bf2f(rc[2 * 84]);
        float hr  = bf2f(rc[3 * 84]);
        float obj = sigm(bf2f(rc[4 * 84]));

        float px = x + (float)i, py = y + (float)j;
        float pw = __expf(wr) * AW9[a], ph = __expf(hr) * AH9[a];
        float areap = pw * ph;

        float maxiou = 0.0f; int mk = -1;
        for (int k = 0; k < K_; k++) {
            const float* R = labS + k * 16;
            float tx = R[1], ty = R[2], tw = R[3], th = R[4];
            if (R[0] != 0.0f) {
                float tlx = fmaxf(px - pw * 0.5f, tx - tw * 0.5f);
                float tly = fmaxf(py - ph * 0.5f, ty - th * 0.5f);
                float brx = fminf(px + pw * 0.5f, tx + tw * 0.5f);
                float bry = fminf(py + ph * 0.5f, ty + th * 0.5f);
                float iw = brx - tlx, ih = bry - tly;
                float inter = (iw > 0.0f && ih > 0.0f) ? iw * ih : 0.0f;
                float iou = inter / (areap + tw * th - inter);
                maxiou = fmaxf(maxiou, iou);
            }
            if (R[5] != 0.0f && (int)R[6] == a && (int)R[7] == i && (int)R[8] == j) mk = k; // last wins
        }
        float objmask = (maxiou > 0.7f) ? 0.0f : 1.0f;

        float* om = d_out + 6 + (size_t)(((b * A_ + a) * F_ + j) * F_ + i) * NCH;
        if (mk >= 0) {
            const float* R = labS + mk * 16;
            float sc = R[13], sc2 = sc * sc;
            float txv = R[9], tyv = R[10], twv = R[11], thv = R[12];
            int cl = (int)R[14];
            lxy = (bce_t(x, txv) + bce_t(y, tyv)) * sc2;
            float dw = wr - twv, dh = hr - thv;
            lwh = 0.5f * sc2 * (dw * dw + dh * dh);
            float pco = fminf(fmaxf(obj, 1e-12f), 1.0f - 1e-7f);
            lobj = -__logf(pco);
            float dx = x - txv, dy = y - tyv, dob = obj - 1.0f;
            l2 = dx * dx + dy * dy + sc2 * (dw * dw + dh * dh) + dob * dob;
            om[0] = x; om[1] = y; om[2] = wr * sc; om[3] = hr * sc; om[4] = obj;
            for (int c = 0; c < 80; c++) {
                float p = sigm(bf2f(rc[(5 + c) * 84]));
                float tcv = (c == cl) ? 1.0f : 0.0f;
                lcls += bce_t(p, tcv);
                float d = p - tcv;
                l2 += d * d;
                om[5 + c] = p;
            }
        } else {
            float oo = obj * objmask;
            if (objmask != 0.0f) {
                float pco = fminf(obj, 1.0f - 1e-7f);
                lobj = -__logf(1.0f - pco);
            }
            l2 = oo * oo;
            om[4] = oo;    // rest already zero-filled
        }
    }

    // wave reduction + atomics
    #pragma unroll
    for (int off = 32; off > 0; off >>= 1) {
        lxy  += __shfl_down(lxy, off);
        lwh  += __shfl_down(lwh, off);
        lobj += __shfl_down(lobj, off);
        lcls += __shfl_down(lcls, off);
        l2   += __shfl_down(l2, off);
    }
    if ((t & 63) == 0) {
        atomicAdd(&d_out[1], lxy);
        atomicAdd(&d_out[2], lwh);
        atomicAdd(&d_out[3], lobj);
        atomicAdd(&d_out[4], lcls);
        atomicAdd(&d_out[5], l2);
        atomicAdd(&d_out[0], lxy + lwh + lobj + lcls);
    }
}

extern "C" void kernel_launch(void* const* d_in, const int* in_sizes, int n_in,
                              void* d_out, int out_size, void* d_ws, size_t ws_size,
                              hipStream_t stream) {
    const float* xin    = (const float*)d_in[0];
    const float* labels = (const float*)d_in[1];
    const float* conv_w = (const float*)d_in[2];
    const float* conv_b = (const float*)d_in[3];
    float* out = (float*)d_out;
    float* ws  = (float*)d_ws;

    prep_kernel<<<258, 256, 0, stream>>>(conv_w, conv_b, labels, ws, out);
    yolo_main<<<B_ * F_, 256, 0, stream>>>(xin, ws, out);
}

// Round 3
// 247.905 us; speedup vs baseline: 2.9543x; 2.3632x over previous
//
#include <hip/hip_runtime.h>
#include <hip/hip_bf16.h>

#define B_   16
#define K_   50
#define CIN  256
#define F_   76
#define A_   3
#define NCH  85
#define OC   255
#define HW   (F_*F_)
#define NBLK (B_*F_)

// ws floats: Wfrag bf16[65536]=f[0..32768) ; bias[32768..33024) ; labrec[33024..45824) ; partials[45824..45824+1216*8)
#define WS_BIAS_F 32768
#define WS_LAB_F  33024
#define WS_PART_F 45824

typedef __attribute__((ext_vector_type(8))) short short8;
typedef __attribute__((ext_vector_type(4))) float f32x4;

__device__ __constant__ float AW9[9] = {1.25f, 2.0f, 4.125f, 3.75f, 7.75f, 7.375f, 14.5f, 19.5f, 46.625f};
__device__ __constant__ float AH9[9] = {1.625f, 3.75f, 2.875f, 7.625f, 5.625f, 14.875f, 11.25f, 24.75f, 40.75f};

__device__ __forceinline__ unsigned short f2bf(float f) {
    union { float f; unsigned int u; } v; v.f = f;
    unsigned int r = v.u + 0x7fffu + ((v.u >> 16) & 1u);
    return (unsigned short)(r >> 16);
}
__device__ __forceinline__ float bf2f(unsigned short b) {
    union { unsigned int u; float f; } v; v.u = ((unsigned int)b) << 16;
    return v.f;
}
__device__ __forceinline__ float sigm(float r) { return 1.0f / (1.0f + __expf(-r)); }
__device__ __forceinline__ float bce_t(float p, float tv) {
    float pc = fminf(fmaxf(p, 1e-12f), 1.0f - 1e-7f);
    return -(tv * __logf(pc) + (1.0f - tv) * __logf(1.0f - pc));
}

// ---------------- prep: W -> bf16 A-fragment order, bias, label records ----------------
__global__ void prep_kernel(const float* __restrict__ conv_w, const float* __restrict__ conv_b,
                            const float* __restrict__ labels, float* __restrict__ ws) {
    int bid = blockIdx.x, t = threadIdx.x;
    if (bid < 256) {
        int idx = bid * 256 + t;
        int mt = idx >> 12, ks = (idx >> 9) & 7, lane = (idx >> 3) & 63, jj = idx & 7;
        int row = mt * 16 + (lane & 15);
        int k   = ks * 32 + (lane >> 4) * 8 + jj;
        float v = (row < OC) ? conv_w[row * CIN + k] : 0.0f;
        ((unsigned short*)ws)[idx] = f2bf(v);
    } else if (bid == 256) {
        ws[WS_BIAS_F + t] = (t < OC) ? conv_b[t] : 0.0f;
    } else { // label records
        for (int idx = t; idx < B_ * K_; idx += 256) {
            const float* L = labels + idx * 5;
            float cls = L[0], xc = L[1], yc = L[2], wl = L[3], hl = L[4];
            float ssum = cls + xc + yc + wl + hl;
            float validf = (ssum > 0.0f) ? 1.0f : 0.0f;
            float tx = xc * F_, ty = yc * F_, tw = wl * F_, th = hl * F_;
            int ii = (int)tx, jj = (int)ty;
            float tarea = tw * th;
            float best = -1.0f; int bn = 0;
            #pragma unroll
            for (int n = 0; n < 9; n++) {
                float inter = fminf(tw, AW9[n]) * fminf(th, AH9[n]);
                float iou = inter / (tarea + AW9[n] * AH9[n] - inter);
                if (iou > best) { best = iou; bn = n; }
            }
            int a = bn % 3;
            float self = (validf != 0.0f && bn < 3) ? 1.0f : 0.0f;
            float* R = ws + WS_LAB_F + idx * 16;
            R[0] = validf; R[1] = tx; R[2] = ty; R[3] = tw; R[4] = th;
            R[5] = self; R[6] = (float)a; R[7] = (float)ii; R[8] = (float)jj;
            R[9] = tx - (float)ii; R[10] = ty - (float)jj;
            R[11] = __logf(tw / AW9[a] + 1e-16f);
            R[12] = __logf(th / AH9[a] + 1e-16f);
            R[13] = sqrtf(2.0f - tarea / (float)HW);
            R[14] = cls; R[15] = 0.0f;
        }
    }
}

// ---------------- fused main ----------------
__global__ __launch_bounds__(256, 3) void yolo_main(const float* __restrict__ xin,
                                                    const float* __restrict__ ws,
                                                    float* __restrict__ d_out,
                                                    float* __restrict__ part) {
    __shared__ __align__(16) unsigned short UNI[OC * 84];    // 42840 B (Xt phase1 / raw phase2)
    __shared__ float labS[K_ * 16];
    __shared__ float biasS[256];
    __shared__ float redS[4][5];

    const int t = threadIdx.x;
    const int b = blockIdx.x / F_;
    const int j = blockIdx.x % F_;
    const float* labrec = ws + WS_LAB_F + b * K_ * 16;

    biasS[t] = ws[WS_BIAS_F + t];
    for (int idx = t; idx < K_ * 16; idx += 256) labS[idx] = labrec[idx];

    // cooperative zero of this block's out_m slabs
    for (int a = 0; a < A_; a++) {
        float2* z = reinterpret_cast<float2*>(d_out + 6 + (size_t)(((b * A_ + a) * F_ + j)) * F_ * NCH);
        for (int idx = t; idx < (F_ * NCH) / 2; idx += 256) z[idx] = make_float2(0.0f, 0.0f);
    }

    // ---------- staging: xin row j -> Xt[i][c] bf16, octet-XOR-swizzled ----------
    for (int idx = t; idx < 32 * F_; idx += 256) {
        int co = idx / F_, i = idx - co * F_;
        const float* xp = xin + ((size_t)b * CIN + co * 8) * HW + j * F_ + i;
        short8 v;
        #pragma unroll
        for (int jj = 0; jj < 8; jj++) v[jj] = (short)f2bf(xp[jj * HW]);
        int phys = co ^ (i & 7);
        *(short8*)&UNI[i * 256 + phys * 8] = v;
    }
    __syncthreads();

    // ---------- MFMA K-loop ----------
    const int w = t >> 6, lane = t & 63, lr = lane & 15, q = lane >> 4;
    f32x4 acc[4][5];
    #pragma unroll
    for (int m = 0; m < 4; m++)
        #pragma unroll
        for (int n = 0; n < 5; n++) acc[m][n] = (f32x4){0.0f, 0.0f, 0.0f, 0.0f};

    const short8* wf = (const short8*)ws;
    #pragma unroll 2
    for (int ks = 0; ks < 8; ks++) {
        short8 afr[4], bfr[5];
        #pragma unroll
        for (int m = 0; m < 4; m++)
            afr[m] = wf[((w * 4 + m) * 8 + ks) * 64 + lane];
        #pragma unroll
        for (int n = 0; n < 5; n++) {
            int nn = n * 16 + lr;
            int phys = (ks * 4 + q) ^ (lr & 7);
            bfr[n] = *(const short8*)&UNI[nn * 256 + phys * 8];
        }
        #pragma unroll
        for (int m = 0; m < 4; m++)
            #pragma unroll
            for (int n = 0; n < 5; n++)
                acc[m][n] = __builtin_amdgcn_mfma_f32_16x16x32_bf16(afr[m], bfr[n], acc[m][n], 0, 0, 0);
    }
    __syncthreads();

    // ---------- epilogue: acc (+bias) -> raw bf16 [o][i], stride 84 ----------
    #pragma unroll
    for (int m = 0; m < 4; m++) {
        #pragma unroll
        for (int n = 0; n < 5; n++) {
            int i = n * 16 + lr;
            if (i < F_) {
                #pragma unroll
                for (int r = 0; r < 4; r++) {
                    int o = (w * 4 + m) * 16 + q * 4 + r;
                    if (o < OC) UNI[o * 84 + i] = f2bf(acc[m][n][r] + biasS[o]);
                }
            }
        }
    }
    __syncthreads();

    // ---------- phase 2: per-cell losses + out_m ----------
    float lxy = 0.0f, lwh = 0.0f, lobj = 0.0f, lcls = 0.0f, l2 = 0.0f;
    if (t < A_ * F_) {
        int a = t / F_, i = t - a * F_;
        const unsigned short* rc = UNI + (a * NCH) * 84 + i;
        float x   = sigm(bf2f(rc[0 * 84]));
        float y   = sigm(bf2f(rc[1 * 84]));
        float wr  = bf2f(rc[2 * 84]);
        float hr  = bf2f(rc[3 * 84]);
        float obj = sigm(bf2f(rc[4 * 84]));

        float px = x + (float)i, py = y + (float)j;
        float pw = __expf(wr) * AW9[a], ph = __expf(hr) * AH9[a];
        float areap = pw * ph;

        float maxiou = 0.0f; int mk = -1;
        for (int k = 0; k < K_; k++) {
            const float* R = labS + k * 16;
            float tx = R[1], ty = R[2], tw = R[3], th = R[4];
            if (R[0] != 0.0f) {
                float tlx = fmaxf(px - pw * 0.5f, tx - tw * 0.5f);
                float tly = fmaxf(py - ph * 0.5f, ty - th * 0.5f);
                float brx = fminf(px + pw * 0.5f, tx + tw * 0.5f);
                float bry = fminf(py + ph * 0.5f, ty + th * 0.5f);
                float iw = brx - tlx, ih = bry - tly;
                float inter = (iw > 0.0f && ih > 0.0f) ? iw * ih : 0.0f;
                float iou = inter / (areap + tw * th - inter);
                maxiou = fmaxf(maxiou, iou);
            }
            if (R[5] != 0.0f && (int)R[6] == a && (int)R[7] == i && (int)R[8] == j) mk = k;
        }
        float objmask = (maxiou > 0.7f) ? 0.0f : 1.0f;

        float* om = d_out + 6 + (size_t)(((b * A_ + a) * F_ + j) * F_ + i) * NCH;
        if (mk >= 0) {
            const float* R = labS + mk * 16;
            float sc = R[13], sc2 = sc * sc;
            float txv = R[9], tyv = R[10], twv = R[11], thv = R[12];
            int cl = (int)R[14];
            lxy = (bce_t(x, txv) + bce_t(y, tyv)) * sc2;
            float dw = wr - twv, dh = hr - thv;
            lwh = 0.5f * sc2 * (dw * dw + dh * dh);
            float pco = fminf(fmaxf(obj, 1e-12f), 1.0f - 1e-7f);
            lobj = -__logf(pco);
            float dx = x - txv, dy = y - tyv, dob = obj - 1.0f;
            l2 = dx * dx + dy * dy + sc2 * (dw * dw + dh * dh) + dob * dob;
            om[0] = x; om[1] = y; om[2] = wr * sc; om[3] = hr * sc; om[4] = obj;
            for (int c = 0; c < 80; c++) {
                float p = sigm(bf2f(rc[(5 + c) * 84]));
                float tcv = (c == cl) ? 1.0f : 0.0f;
                lcls += bce_t(p, tcv);
                float d = p - tcv;
                l2 += d * d;
                om[5 + c] = p;
            }
        } else {
            float oo = obj * objmask;
            if (objmask != 0.0f) {
                float pco = fminf(obj, 1.0f - 1e-7f);
                lobj = -__logf(1.0f - pco);
            }
            l2 = oo * oo;
            om[4] = oo;
        }
    }

    // wave reduce -> LDS -> one partial record per block (NO global atomics)
    #pragma unroll
    for (int off = 32; off > 0; off >>= 1) {
        lxy  += __shfl_down(lxy, off);
        lwh  += __shfl_down(lwh, off);
        lobj += __shfl_down(lobj, off);
        lcls += __shfl_down(lcls, off);
        l2   += __shfl_down(l2, off);
    }
    if (lane == 0) {
        redS[w][0] = lxy; redS[w][1] = lwh; redS[w][2] = lobj;
        redS[w][3] = lcls; redS[w][4] = l2;
    }
    __syncthreads();
    if (t == 0) {
        float* P = part + (size_t)blockIdx.x * 8;
        #pragma unroll
        for (int q2 = 0; q2 < 5; q2++)
            P[q2] = redS[0][q2] + redS[1][q2] + redS[2][q2] + redS[3][q2];
    }
}

// ---------------- finish: reduce 1216 partials -> d_out[0..5] ----------------
__global__ void finish_kernel(const float* __restrict__ part, float* __restrict__ d_out) {
    int t = threadIdx.x;
    float s0 = 0, s1 = 0, s2 = 0, s3 = 0, s4 = 0;
    for (int bidx = t; bidx < NBLK; bidx += 256) {
        const float* P = part + (size_t)bidx * 8;
        s0 += P[0]; s1 += P[1]; s2 += P[2]; s3 += P[3]; s4 += P[4];
    }
    #pragma unroll
    for (int off = 32; off > 0; off >>= 1) {
        s0 += __shfl_down(s0, off); s1 += __shfl_down(s1, off);
        s2 += __shfl_down(s2, off); s3 += __shfl_down(s3, off);
        s4 += __shfl_down(s4, off);
    }
    __shared__ float red[4][5];
    if ((t & 63) == 0) {
        int w = t >> 6;
        red[w][0] = s0; red[w][1] = s1; red[w][2] = s2; red[w][3] = s3; red[w][4] = s4;
    }
    __syncthreads();
    if (t == 0) {
        float r0 = red[0][0] + red[1][0] + red[2][0] + red[3][0];
        float r1 = red[0][1] + red[1][1] + red[2][1] + red[3][1];
        float r2 = red[0][2] + red[1][2] + red[2][2] + red[3][2];
        float r3 = red[0][3] + red[1][3] + red[2][3] + red[3][3];
        float r4 = red[0][4] + red[1][4] + red[2][4] + red[3][4];
        d_out[0] = r0 + r1 + r2 + r3;
        d_out[1] = r0; d_out[2] = r1; d_out[3] = r2; d_out[4] = r3; d_out[5] = r4;
    }
}

extern "C" void kernel_launch(void* const* d_in, const int* in_sizes, int n_in,
                              void* d_out, int out_size, void* d_ws, size_t ws_size,
                              hipStream_t stream) {
    const float* xin    = (const float*)d_in[0];
    const float* labels = (const float*)d_in[1];
    const float* conv_w = (const float*)d_in[2];
    const float* conv_b = (const float*)d_in[3];
    float* out  = (float*)d_out;
    float* ws   = (float*)d_ws;
    float* part = ws + WS_PART_F;

    prep_kernel<<<258, 256, 0, stream>>>(conv_w, conv_b, labels, ws);
    yolo_main<<<NBLK, 256, 0, stream>>>(xin, ws, out, part);
    finish_kernel<<<1, 256, 0, stream>>>(part, out);
}